// Round 1
// baseline (809.148 us; speedup 1.0000x reference)
//
#include <hip/hip_runtime.h>

// Problem constants (match reference)
#define NN    30000
#define EE    480000
#define ETOT  (EE + NN)   // edges + self-loops = 510000
#define GG    64
#define IN_CH 128
#define HID   128
#define HEADS 4
#define F1    (HEADS * HID)   // 512

__device__ __forceinline__ float lrelu(float x) { return x > 0.f ? x : 0.2f * x; }
__device__ __forceinline__ float elu_f(float x) { return x > 0.f ? x : (expf(x) - 1.f); }

// ---------------- GEMM: C[M,N] = A[M,K] @ B[K,N], fp32, 64x64 tile ----------------
__global__ __launch_bounds__(256) void sgemm_k(const float* __restrict__ A,
                                               const float* __restrict__ B,
                                               float* __restrict__ C,
                                               int M, int N, int K)
{
    __shared__ __align__(16) float As[16][68];   // transposed A tile, padded (stride 68 floats = 272B, 16B-mult)
    __shared__ __align__(16) float Bs[16][64];
    const int tid = threadIdx.x;
    const int tx = tid & 15;
    const int ty = tid >> 4;
    const int bm = blockIdx.x * 64;
    const int bn = blockIdx.y * 64;

    float acc[4][4];
#pragma unroll
    for (int i = 0; i < 4; i++)
#pragma unroll
        for (int j = 0; j < 4; j++) acc[i][j] = 0.f;

    const int ar  = tid >> 2;        // 0..63 row within A tile
    const int ak  = (tid & 3) * 4;   // 0,4,8,12 k within tile
    const int bk  = tid >> 4;        // 0..15 k within B tile
    const int bn0 = (tid & 15) * 4;  // col within B tile

    for (int kt = 0; kt < K; kt += 16) {
        float4 av = make_float4(0.f, 0.f, 0.f, 0.f);
        int gr = bm + ar;
        if (gr < M) av = *(const float4*)(A + (size_t)gr * K + kt + ak);
        As[ak + 0][ar] = av.x; As[ak + 1][ar] = av.y;
        As[ak + 2][ar] = av.z; As[ak + 3][ar] = av.w;

        float4 bv = *(const float4*)(B + (size_t)(kt + bk) * N + bn + bn0);
        *(float4*)&Bs[bk][bn0] = bv;
        __syncthreads();

#pragma unroll
        for (int k = 0; k < 16; k++) {
            float4 a = *(const float4*)&As[k][ty * 4];
            float4 b = *(const float4*)&Bs[k][tx * 4];
            acc[0][0] = fmaf(a.x, b.x, acc[0][0]); acc[0][1] = fmaf(a.x, b.y, acc[0][1]);
            acc[0][2] = fmaf(a.x, b.z, acc[0][2]); acc[0][3] = fmaf(a.x, b.w, acc[0][3]);
            acc[1][0] = fmaf(a.y, b.x, acc[1][0]); acc[1][1] = fmaf(a.y, b.y, acc[1][1]);
            acc[1][2] = fmaf(a.y, b.z, acc[1][2]); acc[1][3] = fmaf(a.y, b.w, acc[1][3]);
            acc[2][0] = fmaf(a.z, b.x, acc[2][0]); acc[2][1] = fmaf(a.z, b.y, acc[2][1]);
            acc[2][2] = fmaf(a.z, b.z, acc[2][2]); acc[2][3] = fmaf(a.z, b.w, acc[2][3]);
            acc[3][0] = fmaf(a.w, b.x, acc[3][0]); acc[3][1] = fmaf(a.w, b.y, acc[3][1]);
            acc[3][2] = fmaf(a.w, b.z, acc[3][2]); acc[3][3] = fmaf(a.w, b.w, acc[3][3]);
        }
        __syncthreads();
    }

#pragma unroll
    for (int i = 0; i < 4; i++) {
        int gr = bm + ty * 4 + i;
        if (gr < M) {
            float4 v = make_float4(acc[i][0], acc[i][1], acc[i][2], acc[i][3]);
            *(float4*)(C + (size_t)gr * N + bn + tx * 4) = v;
        }
    }
}

// ---------------- per-node attention scores a_s[n,h], a_d[n,h] ----------------
__global__ __launch_bounds__(128) void att_scores_k(const float* __restrict__ h,
                                                    const float* __restrict__ w_s,
                                                    const float* __restrict__ w_d,
                                                    float* __restrict__ a_s,
                                                    float* __restrict__ a_d,
                                                    int HC, int H)
{
    int n = blockIdx.x, t = threadIdx.x;
    __shared__ float red[128];
    for (int k = 0; k < H; k++) {
        float v = h[(size_t)n * HC + k * 128 + t];
        red[t] = v * w_s[k * 128 + t];
        __syncthreads();
        for (int off = 64; off; off >>= 1) { if (t < off) red[t] += red[t + off]; __syncthreads(); }
        if (t == 0) a_s[(size_t)n * H + k] = red[0];
        __syncthreads();
        red[t] = v * w_d[k * 128 + t];
        __syncthreads();
        for (int off = 64; off; off >>= 1) { if (t < off) red[t] += red[t + off]; __syncthreads(); }
        if (t == 0) a_d[(size_t)n * H + k] = red[0];
        __syncthreads();
    }
}

// ---------------- CSR build ----------------
__global__ void hist_k(const int* __restrict__ ei, int* __restrict__ deg)
{
    int i = blockIdx.x * blockDim.x + threadIdx.x;
    if (i < ETOT) {
        int d = (i < EE) ? ei[EE + i] : (i - EE);
        atomicAdd(&deg[d], 1);
    }
}

__global__ __launch_bounds__(1024) void scan_k(const int* __restrict__ deg, int* __restrict__ rowptr)
{
    __shared__ int sums[1024];
    int t = threadIdx.x;
    const int chunk = (NN + 1023) / 1024;  // 30
    int start = t * chunk;
    int end = min(start + chunk, NN);
    int s = 0;
    for (int i = start; i < end; i++) s += deg[i];
    sums[t] = s;
    __syncthreads();
    for (int off = 1; off < 1024; off <<= 1) {
        int v = (t >= off) ? sums[t - off] : 0;
        __syncthreads();
        sums[t] += v;
        __syncthreads();
    }
    int run = (t == 0) ? 0 : sums[t - 1];
    for (int i = start; i < end; i++) { rowptr[i] = run; run += deg[i]; }
    if (t == 1023) rowptr[NN] = run;
}

__global__ void copy_int_k(const int* __restrict__ a, int* __restrict__ b, int n)
{
    int i = blockIdx.x * blockDim.x + threadIdx.x;
    if (i < n) b[i] = a[i];
}

__global__ void fill_k(const int* __restrict__ ei, int* __restrict__ cursor, int* __restrict__ perm)
{
    int i = blockIdx.x * blockDim.x + threadIdx.x;
    if (i < ETOT) {
        int s, d;
        if (i < EE) { s = ei[i]; d = ei[EE + i]; }
        else        { s = i - EE; d = i - EE; }
        int p = atomicAdd(&cursor[d], 1);
        perm[p] = s;
    }
}

// ---------------- layer 1: per-dst softmax + aggregate (H=4, C=128), ELU fused ----------------
__global__ __launch_bounds__(256) void gat_agg1(const float* __restrict__ h,
                                                const float* __restrict__ a_s,
                                                const float* __restrict__ a_d,
                                                const int* __restrict__ rowptr,
                                                const int* __restrict__ perm,
                                                const float* __restrict__ bias,
                                                float* __restrict__ out)
{
    int n = blockIdx.x, t = threadIdx.x;
    int beg = rowptr[n], end = rowptr[n + 1];
    float ad0 = a_d[n * 4 + 0], ad1 = a_d[n * 4 + 1], ad2 = a_d[n * 4 + 2], ad3 = a_d[n * 4 + 3];

    __shared__ float red[256 * 4];
    __shared__ float smx[4], sden[4];
    __shared__ int   s_src[64];
    __shared__ float s_alpha[64 * 4];

    // pass A: per-head max
    float mx0 = -1e30f, mx1 = -1e30f, mx2 = -1e30f, mx3 = -1e30f;
    for (int j = beg + t; j < end; j += 256) {
        int s = perm[j];
        float4 av = *(const float4*)(a_s + (size_t)s * 4);
        mx0 = fmaxf(mx0, lrelu(av.x + ad0));
        mx1 = fmaxf(mx1, lrelu(av.y + ad1));
        mx2 = fmaxf(mx2, lrelu(av.z + ad2));
        mx3 = fmaxf(mx3, lrelu(av.w + ad3));
    }
    red[t * 4 + 0] = mx0; red[t * 4 + 1] = mx1; red[t * 4 + 2] = mx2; red[t * 4 + 3] = mx3;
    __syncthreads();
    for (int off = 128; off; off >>= 1) {
        if (t < off) {
#pragma unroll
            for (int k = 0; k < 4; k++)
                red[t * 4 + k] = fmaxf(red[t * 4 + k], red[(t + off) * 4 + k]);
        }
        __syncthreads();
    }
    if (t < 4) smx[t] = red[t];
    __syncthreads();
    float M0 = smx[0], M1 = smx[1], M2 = smx[2], M3 = smx[3];

    // pass B: per-head sum of exp
    float s0 = 0.f, s1 = 0.f, s2 = 0.f, s3 = 0.f;
    for (int j = beg + t; j < end; j += 256) {
        int s = perm[j];
        float4 av = *(const float4*)(a_s + (size_t)s * 4);
        s0 += __expf(lrelu(av.x + ad0) - M0);
        s1 += __expf(lrelu(av.y + ad1) - M1);
        s2 += __expf(lrelu(av.z + ad2) - M2);
        s3 += __expf(lrelu(av.w + ad3) - M3);
    }
    red[t * 4 + 0] = s0; red[t * 4 + 1] = s1; red[t * 4 + 2] = s2; red[t * 4 + 3] = s3;
    __syncthreads();
    for (int off = 128; off; off >>= 1) {
        if (t < off) {
#pragma unroll
            for (int k = 0; k < 4; k++)
                red[t * 4 + k] += red[(t + off) * 4 + k];
        }
        __syncthreads();
    }
    if (t < 4) sden[t] = 1.f / (red[t] + 1e-16f);
    __syncthreads();

    // pass C: accumulate out channels; thread t owns channels t and t+256
    float acc0 = 0.f, acc1 = 0.f;
    const int c0 = t, c1 = t + 256;
    const int h0 = t >> 7;  // head of c0 (0 or 1); head of c1 is h0+2
    for (int base = beg; base < end; base += 64) {
        int cl = min(64, end - base);
        __syncthreads();
        if (t < cl) s_src[t] = perm[base + t];
        int j4 = t >> 2;
        if (j4 < cl) {
            int s = perm[base + j4];
            int k = t & 3;
            float e = lrelu(a_s[(size_t)s * 4 + k] + a_d[(size_t)n * 4 + k]);
            s_alpha[j4 * 4 + k] = __expf(e - smx[k]) * sden[k];
        }
        __syncthreads();
        for (int j = 0; j < cl; j++) {
            const float* hr = h + (size_t)s_src[j] * F1;
            acc0 = fmaf(s_alpha[j * 4 + h0],     hr[c0], acc0);
            acc1 = fmaf(s_alpha[j * 4 + h0 + 2], hr[c1], acc1);
        }
    }
    float o0 = acc0 + bias[c0];
    float o1 = acc1 + bias[c1];
    out[(size_t)n * F1 + c0] = elu_f(o0);
    out[(size_t)n * F1 + c1] = elu_f(o1);
}

// ---------------- layer 2: per-dst softmax + aggregate (H=1, C=128), ELU fused ----------------
__global__ __launch_bounds__(128) void gat_agg2(const float* __restrict__ h,
                                                const float* __restrict__ a_s,
                                                const float* __restrict__ a_d,
                                                const int* __restrict__ rowptr,
                                                const int* __restrict__ perm,
                                                const float* __restrict__ bias,
                                                float* __restrict__ out)
{
    int n = blockIdx.x, t = threadIdx.x;
    int beg = rowptr[n], end = rowptr[n + 1];
    float ad = a_d[n];
    __shared__ float red[128];
    __shared__ float sM, sInv;
    __shared__ int   s_src[128];
    __shared__ float s_alpha[128];

    float mx = -1e30f;
    for (int j = beg + t; j < end; j += 128) mx = fmaxf(mx, lrelu(a_s[perm[j]] + ad));
    red[t] = mx; __syncthreads();
    for (int off = 64; off; off >>= 1) { if (t < off) red[t] = fmaxf(red[t], red[t + off]); __syncthreads(); }
    if (t == 0) sM = red[0];
    __syncthreads();
    float M = sM;

    float sm = 0.f;
    for (int j = beg + t; j < end; j += 128) sm += __expf(lrelu(a_s[perm[j]] + ad) - M);
    red[t] = sm; __syncthreads();
    for (int off = 64; off; off >>= 1) { if (t < off) red[t] += red[t + off]; __syncthreads(); }
    if (t == 0) sInv = 1.f / (red[0] + 1e-16f);
    __syncthreads();
    float inv = sInv;

    float acc = 0.f;
    for (int base = beg; base < end; base += 128) {
        int cl = min(128, end - base);
        __syncthreads();
        if (t < cl) {
            int s = perm[base + t];
            s_src[t] = s;
            s_alpha[t] = __expf(lrelu(a_s[s] + ad) - M) * inv;
        }
        __syncthreads();
        for (int j = 0; j < cl; j++)
            acc = fmaf(s_alpha[j], h[(size_t)s_src[j] * HID + t], acc);
    }
    float o = acc + bias[t];
    out[(size_t)n * HID + t] = elu_f(o);
}

// ---------------- pooling + final linear ----------------
__global__ __launch_bounds__(128) void pool_k(const float* __restrict__ out2,
                                              const int* __restrict__ batch,
                                              float* __restrict__ pooled,
                                              float* __restrict__ cnt)
{
    int n = blockIdx.x, t = threadIdx.x;
    int g = batch[n];
    atomicAdd(&pooled[g * HID + t], out2[(size_t)n * HID + t]);
    if (t == 0) atomicAdd(&cnt[g], 1.0f);
}

__global__ void final_k(const float* __restrict__ pooled, const float* __restrict__ cnt,
                        const float* __restrict__ lw, const float* __restrict__ lb,
                        float* __restrict__ outp)
{
    int g = threadIdx.x;
    if (g < GG) {
        float acc = 0.f;
        for (int c = 0; c < HID; c++) acc += pooled[g * HID + c] * lw[c];
        float cc = fmaxf(cnt[g], 1.0f);
        outp[g] = acc / cc + lb[0];
    }
}

// ---------------- launch ----------------
extern "C" void kernel_launch(void* const* d_in, const int* in_sizes, int n_in,
                              void* d_out, int out_size, void* d_ws, size_t ws_size,
                              hipStream_t stream)
{
    const float* x    = (const float*)d_in[0];
    const int*   ei   = (const int*)d_in[1];
    const int*   batch= (const int*)d_in[2];
    const float* W1   = (const float*)d_in[3];
    const float* as1w = (const float*)d_in[4];
    const float* ad1w = (const float*)d_in[5];
    const float* b1   = (const float*)d_in[6];
    const float* W2   = (const float*)d_in[7];
    const float* as2w = (const float*)d_in[8];
    const float* ad2w = (const float*)d_in[9];
    const float* b2   = (const float*)d_in[10];
    const float* lw   = (const float*)d_in[11];
    const float* lb   = (const float*)d_in[12];
    float* outp = (float*)d_out;

    char* w = (char*)d_ws;
    size_t off = 0;
    auto alloc = [&](size_t bytes) -> char* {
        char* p = w + off;
        off += (bytes + 255) & ~(size_t)255;
        return p;
    };
    float* h1     = (float*)alloc((size_t)NN * F1 * 4);   // 61.4 MB; later reused for hh2/out2
    float* out1   = (float*)alloc((size_t)NN * F1 * 4);   // 61.4 MB
    float* a_s1   = (float*)alloc((size_t)NN * 4 * 4);
    float* a_d1   = (float*)alloc((size_t)NN * 4 * 4);
    float* a_s2   = (float*)alloc((size_t)NN * 4);
    float* a_d2   = (float*)alloc((size_t)NN * 4);
    int*   deg    = (int*)alloc((size_t)NN * 4);
    int*   rowptr = (int*)alloc((size_t)(NN + 1) * 4);
    int*   cursor = (int*)alloc((size_t)NN * 4);
    int*   perm   = (int*)alloc((size_t)ETOT * 4);
    float* pooled = (float*)alloc((size_t)GG * HID * 4);
    float* cnt    = (float*)alloc((size_t)GG * 4);
    float* hh2  = h1;                         // reuse: h1 dead after gat_agg1
    float* out2 = h1 + (size_t)NN * HID;      // disjoint from hh2 within h1 region

    hipMemsetAsync(deg, 0, (size_t)NN * 4, stream);
    hipMemsetAsync(pooled, 0, (size_t)GG * HID * 4, stream);
    hipMemsetAsync(cnt, 0, (size_t)GG * 4, stream);

    // layer 1
    dim3 g1((NN + 63) / 64, F1 / 64);
    sgemm_k<<<g1, 256, 0, stream>>>(x, W1, h1, NN, F1, IN_CH);
    att_scores_k<<<NN, 128, 0, stream>>>(h1, as1w, ad1w, a_s1, a_d1, F1, HEADS);

    // CSR by dst (shared across both layers)
    hist_k<<<(ETOT + 255) / 256, 256, 0, stream>>>(ei, deg);
    scan_k<<<1, 1024, 0, stream>>>(deg, rowptr);
    copy_int_k<<<(NN + 255) / 256, 256, 0, stream>>>(rowptr, cursor, NN);
    fill_k<<<(ETOT + 255) / 256, 256, 0, stream>>>(ei, cursor, perm);

    gat_agg1<<<NN, 256, 0, stream>>>(h1, a_s1, a_d1, rowptr, perm, b1, out1);

    // layer 2
    dim3 g2((NN + 63) / 64, HID / 64);
    sgemm_k<<<g2, 256, 0, stream>>>(out1, W2, hh2, NN, HID, F1);
    att_scores_k<<<NN, 128, 0, stream>>>(hh2, as2w, ad2w, a_s2, a_d2, HID, 1);
    gat_agg2<<<NN, 128, 0, stream>>>(hh2, a_s2, a_d2, rowptr, perm, b2, out2);

    // pool + linear
    pool_k<<<NN, 128, 0, stream>>>(out2, batch, pooled, cnt);
    final_k<<<1, 64, 0, stream>>>(pooled, cnt, lw, lb, outp);
}

// Round 2
// 553.480 us; speedup vs baseline: 1.4619x; 1.4619x over previous
//
#include <hip/hip_runtime.h>

// Problem constants (match reference)
#define NN    30000
#define EE    480000
#define ETOT  (EE + NN)   // edges + self-loops = 510000
#define GG    64
#define IN_CH 128
#define HID   128
#define HEADS 4
#define F1    (HEADS * HID)   // 512

__device__ __forceinline__ float lrelu(float x) { return x > 0.f ? x : 0.2f * x; }
__device__ __forceinline__ float elu_f(float x) { return x > 0.f ? x : (expf(x) - 1.f); }

// ---------------- GEMM: C[M,N] = A[M,K] @ B[K,N], fp32, 64x64 tile ----------------
__global__ __launch_bounds__(256) void sgemm_k(const float* __restrict__ A,
                                               const float* __restrict__ B,
                                               float* __restrict__ C,
                                               int M, int N, int K)
{
    __shared__ __align__(16) float As[16][68];
    __shared__ __align__(16) float Bs[16][64];
    const int tid = threadIdx.x;
    const int tx = tid & 15;
    const int ty = tid >> 4;
    const int bm = blockIdx.x * 64;
    const int bn = blockIdx.y * 64;

    float acc[4][4];
#pragma unroll
    for (int i = 0; i < 4; i++)
#pragma unroll
        for (int j = 0; j < 4; j++) acc[i][j] = 0.f;

    const int ar  = tid >> 2;
    const int ak  = (tid & 3) * 4;
    const int bk  = tid >> 4;
    const int bn0 = (tid & 15) * 4;

    for (int kt = 0; kt < K; kt += 16) {
        float4 av = make_float4(0.f, 0.f, 0.f, 0.f);
        int gr = bm + ar;
        if (gr < M) av = *(const float4*)(A + (size_t)gr * K + kt + ak);
        As[ak + 0][ar] = av.x; As[ak + 1][ar] = av.y;
        As[ak + 2][ar] = av.z; As[ak + 3][ar] = av.w;

        float4 bv = *(const float4*)(B + (size_t)(kt + bk) * N + bn + bn0);
        *(float4*)&Bs[bk][bn0] = bv;
        __syncthreads();

#pragma unroll
        for (int k = 0; k < 16; k++) {
            float4 a = *(const float4*)&As[k][ty * 4];
            float4 b = *(const float4*)&Bs[k][tx * 4];
            acc[0][0] = fmaf(a.x, b.x, acc[0][0]); acc[0][1] = fmaf(a.x, b.y, acc[0][1]);
            acc[0][2] = fmaf(a.x, b.z, acc[0][2]); acc[0][3] = fmaf(a.x, b.w, acc[0][3]);
            acc[1][0] = fmaf(a.y, b.x, acc[1][0]); acc[1][1] = fmaf(a.y, b.y, acc[1][1]);
            acc[1][2] = fmaf(a.y, b.z, acc[1][2]); acc[1][3] = fmaf(a.y, b.w, acc[1][3]);
            acc[2][0] = fmaf(a.z, b.x, acc[2][0]); acc[2][1] = fmaf(a.z, b.y, acc[2][1]);
            acc[2][2] = fmaf(a.z, b.z, acc[2][2]); acc[2][3] = fmaf(a.z, b.w, acc[2][3]);
            acc[3][0] = fmaf(a.w, b.x, acc[3][0]); acc[3][1] = fmaf(a.w, b.y, acc[3][1]);
            acc[3][2] = fmaf(a.w, b.z, acc[3][2]); acc[3][3] = fmaf(a.w, b.w, acc[3][3]);
        }
        __syncthreads();
    }

#pragma unroll
    for (int i = 0; i < 4; i++) {
        int gr = bm + ty * 4 + i;
        if (gr < M) {
            float4 v = make_float4(acc[i][0], acc[i][1], acc[i][2], acc[i][3]);
            *(float4*)(C + (size_t)gr * N + bn + tx * 4) = v;
        }
    }
}

// ---------------- per-node attention scores: one wave per (node, head) ----------------
// block = H waves of 64 lanes; wave w handles head w; lane l covers channels l, l+64
__global__ void att_scores_k(const float* __restrict__ h,
                             const float* __restrict__ w_s,
                             const float* __restrict__ w_d,
                             float* __restrict__ a_s,
                             float* __restrict__ a_d,
                             int H)
{
    int n = blockIdx.x;
    int wave = threadIdx.x >> 6;
    int l = threadIdx.x & 63;
    const float* hr = h + (size_t)n * (H * 128) + wave * 128;
    float h0 = hr[l], h1 = hr[l + 64];
    float vs = h0 * w_s[wave * 128 + l] + h1 * w_s[wave * 128 + l + 64];
    float vd = h0 * w_d[wave * 128 + l] + h1 * w_d[wave * 128 + l + 64];
#pragma unroll
    for (int off = 32; off; off >>= 1) {
        vs += __shfl_down(vs, off);
        vd += __shfl_down(vd, off);
    }
    if (l == 0) {
        a_s[(size_t)n * H + wave] = vs;
        a_d[(size_t)n * H + wave] = vd;
    }
}

// ---------------- CSR build ----------------
__global__ void hist_k(const int* __restrict__ ei, int* __restrict__ deg)
{
    int i = blockIdx.x * blockDim.x + threadIdx.x;
    if (i < ETOT) {
        int d = (i < EE) ? ei[EE + i] : (i - EE);
        atomicAdd(&deg[d], 1);
    }
}

__global__ __launch_bounds__(1024) void scan_k(const int* __restrict__ deg, int* __restrict__ rowptr)
{
    __shared__ int sums[1024];
    int t = threadIdx.x;
    const int chunk = (NN + 1023) / 1024;  // 30
    int start = t * chunk;
    int end = min(start + chunk, NN);
    int s = 0;
    for (int i = start; i < end; i++) s += deg[i];
    sums[t] = s;
    __syncthreads();
    for (int off = 1; off < 1024; off <<= 1) {
        int v = (t >= off) ? sums[t - off] : 0;
        __syncthreads();
        sums[t] += v;
        __syncthreads();
    }
    int run = (t == 0) ? 0 : sums[t - 1];
    for (int i = start; i < end; i++) { rowptr[i] = run; run += deg[i]; }
    if (t == 1023) rowptr[NN] = run;
}

__global__ void copy_int_k(const int* __restrict__ a, int* __restrict__ b, int n)
{
    int i = blockIdx.x * blockDim.x + threadIdx.x;
    if (i < n) b[i] = a[i];
}

__global__ void fill_k(const int* __restrict__ ei, int* __restrict__ cursor, int* __restrict__ perm)
{
    int i = blockIdx.x * blockDim.x + threadIdx.x;
    if (i < ETOT) {
        int s, d;
        if (i < EE) { s = ei[i]; d = ei[EE + i]; }
        else        { s = i - EE; d = i - EE; }
        int p = atomicAdd(&cursor[d], 1);
        perm[p] = s;
    }
}

// ---------------- layer 1: per-dst softmax + aggregate (H=4, C=128), ELU fused ----------------
__global__ __launch_bounds__(256) void gat_agg1(const float* __restrict__ h,
                                                const float* __restrict__ a_s,
                                                const float* __restrict__ a_d,
                                                const int* __restrict__ rowptr,
                                                const int* __restrict__ perm,
                                                const float* __restrict__ bias,
                                                float* __restrict__ out)
{
    int n = blockIdx.x, t = threadIdx.x;
    int beg = rowptr[n], end = rowptr[n + 1];
    float ad0 = a_d[n * 4 + 0], ad1 = a_d[n * 4 + 1], ad2 = a_d[n * 4 + 2], ad3 = a_d[n * 4 + 3];

    __shared__ float red[256 * 4];
    __shared__ float smx[4], sden[4];
    __shared__ int   s_src[64];
    __shared__ float s_alpha[64 * 4];

    // pass A: per-head max
    float mx0 = -1e30f, mx1 = -1e30f, mx2 = -1e30f, mx3 = -1e30f;
    for (int j = beg + t; j < end; j += 256) {
        int s = perm[j];
        float4 av = *(const float4*)(a_s + (size_t)s * 4);
        mx0 = fmaxf(mx0, lrelu(av.x + ad0));
        mx1 = fmaxf(mx1, lrelu(av.y + ad1));
        mx2 = fmaxf(mx2, lrelu(av.z + ad2));
        mx3 = fmaxf(mx3, lrelu(av.w + ad3));
    }
    red[t * 4 + 0] = mx0; red[t * 4 + 1] = mx1; red[t * 4 + 2] = mx2; red[t * 4 + 3] = mx3;
    __syncthreads();
    for (int off = 128; off; off >>= 1) {
        if (t < off) {
#pragma unroll
            for (int k = 0; k < 4; k++)
                red[t * 4 + k] = fmaxf(red[t * 4 + k], red[(t + off) * 4 + k]);
        }
        __syncthreads();
    }
    if (t < 4) smx[t] = red[t];
    __syncthreads();
    float M0 = smx[0], M1 = smx[1], M2 = smx[2], M3 = smx[3];

    // pass B: per-head sum of exp
    float s0 = 0.f, s1 = 0.f, s2 = 0.f, s3 = 0.f;
    for (int j = beg + t; j < end; j += 256) {
        int s = perm[j];
        float4 av = *(const float4*)(a_s + (size_t)s * 4);
        s0 += __expf(lrelu(av.x + ad0) - M0);
        s1 += __expf(lrelu(av.y + ad1) - M1);
        s2 += __expf(lrelu(av.z + ad2) - M2);
        s3 += __expf(lrelu(av.w + ad3) - M3);
    }
    red[t * 4 + 0] = s0; red[t * 4 + 1] = s1; red[t * 4 + 2] = s2; red[t * 4 + 3] = s3;
    __syncthreads();
    for (int off = 128; off; off >>= 1) {
        if (t < off) {
#pragma unroll
            for (int k = 0; k < 4; k++)
                red[t * 4 + k] += red[(t + off) * 4 + k];
        }
        __syncthreads();
    }
    if (t < 4) sden[t] = 1.f / (red[t] + 1e-16f);
    __syncthreads();

    // pass C: accumulate out channels; thread t owns channels t and t+256
    float acc0 = 0.f, acc1 = 0.f;
    const int c0 = t, c1 = t + 256;
    const int h0 = t >> 7;
    for (int base = beg; base < end; base += 64) {
        int cl = min(64, end - base);
        __syncthreads();
        if (t < cl) s_src[t] = perm[base + t];
        int j4 = t >> 2;
        if (j4 < cl) {
            int s = perm[base + j4];
            int k = t & 3;
            float e = lrelu(a_s[(size_t)s * 4 + k] + a_d[(size_t)n * 4 + k]);
            s_alpha[j4 * 4 + k] = __expf(e - smx[k]) * sden[k];
        }
        __syncthreads();
        for (int j = 0; j < cl; j++) {
            const float* hr = h + (size_t)s_src[j] * F1;
            acc0 = fmaf(s_alpha[j * 4 + h0],     hr[c0], acc0);
            acc1 = fmaf(s_alpha[j * 4 + h0 + 2], hr[c1], acc1);
        }
    }
    float o0 = acc0 + bias[c0];
    float o1 = acc1 + bias[c1];
    out[(size_t)n * F1 + c0] = elu_f(o0);
    out[(size_t)n * F1 + c1] = elu_f(o1);
}

// ---------------- layer 2: per-dst softmax + aggregate (H=1, C=128), ELU fused ----------------
__global__ __launch_bounds__(128) void gat_agg2(const float* __restrict__ h,
                                                const float* __restrict__ a_s,
                                                const float* __restrict__ a_d,
                                                const int* __restrict__ rowptr,
                                                const int* __restrict__ perm,
                                                const float* __restrict__ bias,
                                                float* __restrict__ out)
{
    int n = blockIdx.x, t = threadIdx.x;
    int beg = rowptr[n], end = rowptr[n + 1];
    float ad = a_d[n];
    __shared__ float red[128];
    __shared__ float sM, sInv;
    __shared__ int   s_src[128];
    __shared__ float s_alpha[128];

    float mx = -1e30f;
    for (int j = beg + t; j < end; j += 128) mx = fmaxf(mx, lrelu(a_s[perm[j]] + ad));
    red[t] = mx; __syncthreads();
    for (int off = 64; off; off >>= 1) { if (t < off) red[t] = fmaxf(red[t], red[t + off]); __syncthreads(); }
    if (t == 0) sM = red[0];
    __syncthreads();
    float M = sM;

    float sm = 0.f;
    for (int j = beg + t; j < end; j += 128) sm += __expf(lrelu(a_s[perm[j]] + ad) - M);
    red[t] = sm; __syncthreads();
    for (int off = 64; off; off >>= 1) { if (t < off) red[t] += red[t + off]; __syncthreads(); }
    if (t == 0) sInv = 1.f / (red[0] + 1e-16f);
    __syncthreads();
    float inv = sInv;

    float acc = 0.f;
    for (int base = beg; base < end; base += 128) {
        int cl = min(128, end - base);
        __syncthreads();
        if (t < cl) {
            int s = perm[base + t];
            s_src[t] = s;
            s_alpha[t] = __expf(lrelu(a_s[s] + ad) - M) * inv;
        }
        __syncthreads();
        for (int j = 0; j < cl; j++)
            acc = fmaf(s_alpha[j], h[(size_t)s_src[j] * HID + t], acc);
    }
    float o = acc + bias[t];
    out[(size_t)n * HID + t] = elu_f(o);
}

// ---------------- segmented pooling (batch is sorted) ----------------
// Each block owns NPB consecutive nodes; thread t owns channel t; flush one
// atomic per (block, graph-boundary). ~32x fewer atomics than per-node.
#define NPB 64
__global__ __launch_bounds__(128) void pool_seg_k(const float* __restrict__ out2,
                                                  const int* __restrict__ batch,
                                                  float* __restrict__ pooled,
                                                  float* __restrict__ cnt)
{
    int n0 = blockIdx.x * NPB;
    int n1 = min(n0 + NPB, NN);
    if (n0 >= n1) return;
    int t = threadIdx.x;
    int cur = batch[n0];
    float acc = 0.f;
    int count = 0;
    for (int n = n0; n < n1; n++) {
        int g = batch[n];
        if (g != cur) {
            atomicAdd(&pooled[cur * HID + t], acc);
            if (t == 0) atomicAdd(&cnt[cur], (float)count);
            acc = 0.f; count = 0; cur = g;
        }
        acc += out2[(size_t)n * HID + t];
        count++;
    }
    atomicAdd(&pooled[cur * HID + t], acc);
    if (t == 0) atomicAdd(&cnt[cur], (float)count);
}

__global__ void final_k(const float* __restrict__ pooled, const float* __restrict__ cnt,
                        const float* __restrict__ lw, const float* __restrict__ lb,
                        float* __restrict__ outp)
{
    int g = threadIdx.x;
    if (g < GG) {
        float acc = 0.f;
        for (int c = 0; c < HID; c++) acc += pooled[g * HID + c] * lw[c];
        float cc = fmaxf(cnt[g], 1.0f);
        outp[g] = acc / cc + lb[0];
    }
}

// ---------------- launch ----------------
extern "C" void kernel_launch(void* const* d_in, const int* in_sizes, int n_in,
                              void* d_out, int out_size, void* d_ws, size_t ws_size,
                              hipStream_t stream)
{
    const float* x    = (const float*)d_in[0];
    const int*   ei   = (const int*)d_in[1];
    const int*   batch= (const int*)d_in[2];
    const float* W1   = (const float*)d_in[3];
    const float* as1w = (const float*)d_in[4];
    const float* ad1w = (const float*)d_in[5];
    const float* b1   = (const float*)d_in[6];
    const float* W2   = (const float*)d_in[7];
    const float* as2w = (const float*)d_in[8];
    const float* ad2w = (const float*)d_in[9];
    const float* b2   = (const float*)d_in[10];
    const float* lw   = (const float*)d_in[11];
    const float* lb   = (const float*)d_in[12];
    float* outp = (float*)d_out;

    char* w = (char*)d_ws;
    size_t off = 0;
    auto alloc = [&](size_t bytes) -> char* {
        char* p = w + off;
        off += (bytes + 255) & ~(size_t)255;
        return p;
    };
    float* h1     = (float*)alloc((size_t)NN * F1 * 4);   // 61.4 MB; later reused for hh2/out2
    float* out1   = (float*)alloc((size_t)NN * F1 * 4);   // 61.4 MB
    float* a_s1   = (float*)alloc((size_t)NN * 4 * 4);
    float* a_d1   = (float*)alloc((size_t)NN * 4 * 4);
    float* a_s2   = (float*)alloc((size_t)NN * 4);
    float* a_d2   = (float*)alloc((size_t)NN * 4);
    int*   deg    = (int*)alloc((size_t)NN * 4);
    int*   rowptr = (int*)alloc((size_t)(NN + 1) * 4);
    int*   cursor = (int*)alloc((size_t)NN * 4);
    int*   perm   = (int*)alloc((size_t)ETOT * 4);
    float* pooled = (float*)alloc((size_t)GG * HID * 4);
    float* cnt    = (float*)alloc((size_t)GG * 4);
    float* hh2  = h1;                         // reuse: h1 dead after gat_agg1
    float* out2 = h1 + (size_t)NN * HID;      // disjoint from hh2 within h1 region

    hipMemsetAsync(deg, 0, (size_t)NN * 4, stream);
    hipMemsetAsync(pooled, 0, (size_t)GG * HID * 4, stream);
    hipMemsetAsync(cnt, 0, (size_t)GG * 4, stream);

    // layer 1
    dim3 g1((NN + 63) / 64, F1 / 64);
    sgemm_k<<<g1, 256, 0, stream>>>(x, W1, h1, NN, F1, IN_CH);
    att_scores_k<<<NN, HEADS * 64, 0, stream>>>(h1, as1w, ad1w, a_s1, a_d1, HEADS);

    // CSR by dst (shared across both layers)
    hist_k<<<(ETOT + 255) / 256, 256, 0, stream>>>(ei, deg);
    scan_k<<<1, 1024, 0, stream>>>(deg, rowptr);
    copy_int_k<<<(NN + 255) / 256, 256, 0, stream>>>(rowptr, cursor, NN);
    fill_k<<<(ETOT + 255) / 256, 256, 0, stream>>>(ei, cursor, perm);

    gat_agg1<<<NN, 256, 0, stream>>>(h1, a_s1, a_d1, rowptr, perm, b1, out1);

    // layer 2
    dim3 g2((NN + 63) / 64, HID / 64);
    sgemm_k<<<g2, 256, 0, stream>>>(out1, W2, hh2, NN, HID, F1);
    att_scores_k<<<NN, 64, 0, stream>>>(hh2, as2w, ad2w, a_s2, a_d2, 1);
    gat_agg2<<<NN, 128, 0, stream>>>(hh2, a_s2, a_d2, rowptr, perm, b2, out2);

    // pool + linear
    pool_seg_k<<<(NN + NPB - 1) / NPB, 128, 0, stream>>>(out2, batch, pooled, cnt);
    final_k<<<1, 64, 0, stream>>>(pooled, cnt, lw, lb, outp);
}

// Round 3
// 497.620 us; speedup vs baseline: 1.6260x; 1.1123x over previous
//
#include <hip/hip_runtime.h>

// Problem constants (match reference)
#define NN    30000
#define EE    480000
#define ETOT  (EE + NN)   // edges + self-loops = 510000
#define GG    64
#define IN_CH 128
#define HID   128
#define HEADS 4
#define F1    (HEADS * HID)   // 512

__device__ __forceinline__ float lrelu(float x) { return x > 0.f ? x : 0.2f * x; }
__device__ __forceinline__ float elu_f(float x) { return x > 0.f ? x : (expf(x) - 1.f); }

// ---------------- generalized GEMM: C[M,N] = A[M,K] @ B[K,N] (+bias, elu), 64x64 tile ----
// blockIdx.z selects a head: base pointers get +z*zOff (column offsets within wider rows).
__global__ __launch_bounds__(256) void gemm_generic(const float* __restrict__ A, int lda, int zA,
                                                    const float* __restrict__ B, int ldb, int zB,
                                                    float* __restrict__ C, int ldc, int zC,
                                                    const float* __restrict__ bias, int zBias,
                                                    int M, int N, int K, int do_elu)
{
    A += (size_t)blockIdx.z * zA;
    B += (size_t)blockIdx.z * zB;
    C += (size_t)blockIdx.z * zC;
    if (bias) bias += (size_t)blockIdx.z * zBias;

    __shared__ __align__(16) float As[16][68];
    __shared__ __align__(16) float Bs[16][64];
    const int tid = threadIdx.x;
    const int tx = tid & 15;
    const int ty = tid >> 4;
    const int bm = blockIdx.x * 64;
    const int bn = blockIdx.y * 64;

    float acc[4][4];
#pragma unroll
    for (int i = 0; i < 4; i++)
#pragma unroll
        for (int j = 0; j < 4; j++) acc[i][j] = 0.f;

    const int ar  = tid >> 2;
    const int ak  = (tid & 3) * 4;
    const int bk  = tid >> 4;
    const int bn0 = (tid & 15) * 4;

    for (int kt = 0; kt < K; kt += 16) {
        float4 av = make_float4(0.f, 0.f, 0.f, 0.f);
        int gr = bm + ar;
        if (gr < M) av = *(const float4*)(A + (size_t)gr * lda + kt + ak);
        As[ak + 0][ar] = av.x; As[ak + 1][ar] = av.y;
        As[ak + 2][ar] = av.z; As[ak + 3][ar] = av.w;

        float4 bv = *(const float4*)(B + (size_t)(kt + bk) * ldb + bn + bn0);
        *(float4*)&Bs[bk][bn0] = bv;
        __syncthreads();

#pragma unroll
        for (int k = 0; k < 16; k++) {
            float4 a = *(const float4*)&As[k][ty * 4];
            float4 b = *(const float4*)&Bs[k][tx * 4];
            acc[0][0] = fmaf(a.x, b.x, acc[0][0]); acc[0][1] = fmaf(a.x, b.y, acc[0][1]);
            acc[0][2] = fmaf(a.x, b.z, acc[0][2]); acc[0][3] = fmaf(a.x, b.w, acc[0][3]);
            acc[1][0] = fmaf(a.y, b.x, acc[1][0]); acc[1][1] = fmaf(a.y, b.y, acc[1][1]);
            acc[1][2] = fmaf(a.y, b.z, acc[1][2]); acc[1][3] = fmaf(a.y, b.w, acc[1][3]);
            acc[2][0] = fmaf(a.z, b.x, acc[2][0]); acc[2][1] = fmaf(a.z, b.y, acc[2][1]);
            acc[2][2] = fmaf(a.z, b.z, acc[2][2]); acc[2][3] = fmaf(a.z, b.w, acc[2][3]);
            acc[3][0] = fmaf(a.w, b.x, acc[3][0]); acc[3][1] = fmaf(a.w, b.y, acc[3][1]);
            acc[3][2] = fmaf(a.w, b.z, acc[3][2]); acc[3][3] = fmaf(a.w, b.w, acc[3][3]);
        }
        __syncthreads();
    }

    float4 bb = make_float4(0.f, 0.f, 0.f, 0.f);
    if (bias) bb = *(const float4*)(bias + bn + tx * 4);
#pragma unroll
    for (int i = 0; i < 4; i++) {
        int gr = bm + ty * 4 + i;
        if (gr < M) {
            float4 v = make_float4(acc[i][0] + bb.x, acc[i][1] + bb.y,
                                   acc[i][2] + bb.z, acc[i][3] + bb.w);
            if (do_elu) { v.x = elu_f(v.x); v.y = elu_f(v.y); v.z = elu_f(v.z); v.w = elu_f(v.w); }
            *(float4*)(C + (size_t)gr * ldc + bn + tx * 4) = v;
        }
    }
}

// ---------------- fold attention vectors through W1: wt[sd][h][i] = sum_c W1[i,h*128+c]*att[h,c]
__global__ void prep_att_k(const float* __restrict__ W1,
                           const float* __restrict__ att_s,
                           const float* __restrict__ att_d,
                           float* __restrict__ wt)   // [2][4][128]
{
    int b = blockIdx.x;      // 0..7
    int h = b & 3, sd = b >> 2;
    int i = threadIdx.x;     // input channel
    const float* att = (sd ? att_d : att_s) + h * 128;
    const float* wr = W1 + (size_t)i * F1 + h * 128;
    float acc = 0.f;
    for (int c = 0; c < 128; c++) acc = fmaf(wr[c], att[c], acc);
    wt[sd * 512 + h * 128 + i] = acc;
}

// ---------------- layer-1 scores directly from x: a_s1[n,h] = x[n,:]*wt_s[h,:]
__global__ __launch_bounds__(128) void score1_k(const float* __restrict__ x,
                                                const float* __restrict__ wt,
                                                float* __restrict__ a_s,
                                                float* __restrict__ a_d)
{
    __shared__ float swt[1024];
    int t = threadIdx.x;
#pragma unroll
    for (int i = 0; i < 8; i++) swt[t + i * 128] = wt[t + i * 128];
    __syncthreads();
    int node = blockIdx.x * 16 + (t >> 3);
    int q = t & 7;
    int h = q & 3, sd = q >> 2;
    if (node >= NN) return;
    const float* xr = x + (size_t)node * IN_CH;
    const float* wr = swt + sd * 512 + h * 128;
    float acc = 0.f;
    for (int c = 0; c < 128; c++) acc = fmaf(xr[c], wr[c], acc);
    if (sd == 0) a_s[node * 4 + h] = acc;
    else         a_d[node * 4 + h] = acc;
}

// ---------------- per-node attention scores for layer 2 (H=1): one wave per node -------
__global__ void att_scores_k(const float* __restrict__ h,
                             const float* __restrict__ w_s,
                             const float* __restrict__ w_d,
                             float* __restrict__ a_s,
                             float* __restrict__ a_d)
{
    int n = blockIdx.x;
    int l = threadIdx.x & 63;
    const float* hr = h + (size_t)n * 128;
    float h0 = hr[l], h1 = hr[l + 64];
    float vs = h0 * w_s[l] + h1 * w_s[l + 64];
    float vd = h0 * w_d[l] + h1 * w_d[l + 64];
#pragma unroll
    for (int off = 32; off; off >>= 1) {
        vs += __shfl_down(vs, off);
        vd += __shfl_down(vd, off);
    }
    if (l == 0) { a_s[n] = vs; a_d[n] = vd; }
}

// ---------------- CSR build ----------------
__global__ void hist_k(const int* __restrict__ ei, int* __restrict__ deg)
{
    int i = blockIdx.x * blockDim.x + threadIdx.x;
    if (i < ETOT) {
        int d = (i < EE) ? ei[EE + i] : (i - EE);
        atomicAdd(&deg[d], 1);
    }
}

__global__ __launch_bounds__(1024) void scan_k(const int* __restrict__ deg, int* __restrict__ rowptr)
{
    __shared__ int sums[1024];
    int t = threadIdx.x;
    const int chunk = (NN + 1023) / 1024;  // 30
    int start = t * chunk;
    int end = min(start + chunk, NN);
    int s = 0;
    for (int i = start; i < end; i++) s += deg[i];
    sums[t] = s;
    __syncthreads();
    for (int off = 1; off < 1024; off <<= 1) {
        int v = (t >= off) ? sums[t - off] : 0;
        __syncthreads();
        sums[t] += v;
        __syncthreads();
    }
    int run = (t == 0) ? 0 : sums[t - 1];
    for (int i = start; i < end; i++) { rowptr[i] = run; run += deg[i]; }
    if (t == 1023) rowptr[NN] = run;
}

__global__ void copy_int_k(const int* __restrict__ a, int* __restrict__ b, int n)
{
    int i = blockIdx.x * blockDim.x + threadIdx.x;
    if (i < n) b[i] = a[i];
}

__global__ void fill_k(const int* __restrict__ ei, int* __restrict__ cursor, int* __restrict__ perm)
{
    int i = blockIdx.x * blockDim.x + threadIdx.x;
    if (i < ETOT) {
        int s, d;
        if (i < EE) { s = ei[i]; d = ei[EE + i]; }
        else        { s = i - EE; d = i - EE; }
        int p = atomicAdd(&cursor[d], 1);
        perm[p] = s;
    }
}

// ---------------- layer 1: softmax + aggregate x (not h!) into agg[N,4,128] ------------
// Wave w: channels c = (w&1)*64 + lane; heads (w>>1) and (w>>1)+2.
__global__ __launch_bounds__(256) void gat_agg1x(const float* __restrict__ x,
                                                 const float* __restrict__ a_s,
                                                 const float* __restrict__ a_d,
                                                 const int* __restrict__ rowptr,
                                                 const int* __restrict__ perm,
                                                 float* __restrict__ agg)
{
    int n = blockIdx.x, t = threadIdx.x;
    int beg = rowptr[n], end = rowptr[n + 1];
    float ad0 = a_d[n * 4 + 0], ad1 = a_d[n * 4 + 1], ad2 = a_d[n * 4 + 2], ad3 = a_d[n * 4 + 3];

    __shared__ float red[256 * 4];
    __shared__ float smx[4], sden[4];
    __shared__ int   s_src[64];
    __shared__ float s_alpha[64 * 4];

    // pass A: per-head max
    float mx0 = -1e30f, mx1 = -1e30f, mx2 = -1e30f, mx3 = -1e30f;
    for (int j = beg + t; j < end; j += 256) {
        int s = perm[j];
        float4 av = *(const float4*)(a_s + (size_t)s * 4);
        mx0 = fmaxf(mx0, lrelu(av.x + ad0));
        mx1 = fmaxf(mx1, lrelu(av.y + ad1));
        mx2 = fmaxf(mx2, lrelu(av.z + ad2));
        mx3 = fmaxf(mx3, lrelu(av.w + ad3));
    }
    red[t * 4 + 0] = mx0; red[t * 4 + 1] = mx1; red[t * 4 + 2] = mx2; red[t * 4 + 3] = mx3;
    __syncthreads();
    for (int off = 128; off; off >>= 1) {
        if (t < off) {
#pragma unroll
            for (int k = 0; k < 4; k++)
                red[t * 4 + k] = fmaxf(red[t * 4 + k], red[(t + off) * 4 + k]);
        }
        __syncthreads();
    }
    if (t < 4) smx[t] = red[t];
    __syncthreads();
    float M0 = smx[0], M1 = smx[1], M2 = smx[2], M3 = smx[3];

    // pass B: per-head sum of exp
    float s0 = 0.f, s1 = 0.f, s2 = 0.f, s3 = 0.f;
    for (int j = beg + t; j < end; j += 256) {
        int s = perm[j];
        float4 av = *(const float4*)(a_s + (size_t)s * 4);
        s0 += __expf(lrelu(av.x + ad0) - M0);
        s1 += __expf(lrelu(av.y + ad1) - M1);
        s2 += __expf(lrelu(av.z + ad2) - M2);
        s3 += __expf(lrelu(av.w + ad3) - M3);
    }
    red[t * 4 + 0] = s0; red[t * 4 + 1] = s1; red[t * 4 + 2] = s2; red[t * 4 + 3] = s3;
    __syncthreads();
    for (int off = 128; off; off >>= 1) {
        if (t < off) {
#pragma unroll
            for (int k = 0; k < 4; k++)
                red[t * 4 + k] += red[(t + off) * 4 + k];
        }
        __syncthreads();
    }
    if (t < 4) sden[t] = 1.f / (red[t] + 1e-16f);
    __syncthreads();

    // pass C: acc over x[src][c] — one 4B load feeds TWO fmas (heads h0, h0+2)
    const int wave = t >> 6;
    const int c = (wave & 1) * 64 + (t & 63);
    const int h0 = wave >> 1;           // heads h0 and h0+2
    float acc0 = 0.f, acc1 = 0.f;
    for (int base = beg; base < end; base += 64) {
        int cl = min(64, end - base);
        __syncthreads();
        if (t < cl) s_src[t] = perm[base + t];
        int j4 = t >> 2;
        if (j4 < cl) {
            int s = perm[base + j4];
            int k = t & 3;
            float e = lrelu(a_s[(size_t)s * 4 + k] + a_d[(size_t)n * 4 + k]);
            s_alpha[j4 * 4 + k] = __expf(e - smx[k]) * sden[k];
        }
        __syncthreads();
        for (int j = 0; j < cl; j++) {
            float v = x[(size_t)s_src[j] * IN_CH + c];
            acc0 = fmaf(s_alpha[j * 4 + h0],     v, acc0);
            acc1 = fmaf(s_alpha[j * 4 + h0 + 2], v, acc1);
        }
    }
    agg[((size_t)n * 4 + h0)     * 128 + c] = acc0;
    agg[((size_t)n * 4 + h0 + 2) * 128 + c] = acc1;
}

// ---------------- layer 2: per-dst softmax + aggregate (H=1, C=128), ELU fused ---------
__global__ __launch_bounds__(128) void gat_agg2(const float* __restrict__ h,
                                                const float* __restrict__ a_s,
                                                const float* __restrict__ a_d,
                                                const int* __restrict__ rowptr,
                                                const int* __restrict__ perm,
                                                const float* __restrict__ bias,
                                                float* __restrict__ out)
{
    int n = blockIdx.x, t = threadIdx.x;
    int beg = rowptr[n], end = rowptr[n + 1];
    float ad = a_d[n];
    __shared__ float red[128];
    __shared__ float sM, sInv;
    __shared__ int   s_src[128];
    __shared__ float s_alpha[128];

    float mx = -1e30f;
    for (int j = beg + t; j < end; j += 128) mx = fmaxf(mx, lrelu(a_s[perm[j]] + ad));
    red[t] = mx; __syncthreads();
    for (int off = 64; off; off >>= 1) { if (t < off) red[t] = fmaxf(red[t], red[t + off]); __syncthreads(); }
    if (t == 0) sM = red[0];
    __syncthreads();
    float M = sM;

    float sm = 0.f;
    for (int j = beg + t; j < end; j += 128) sm += __expf(lrelu(a_s[perm[j]] + ad) - M);
    red[t] = sm; __syncthreads();
    for (int off = 64; off; off >>= 1) { if (t < off) red[t] += red[t + off]; __syncthreads(); }
    if (t == 0) sInv = 1.f / (red[0] + 1e-16f);
    __syncthreads();
    float inv = sInv;

    float acc = 0.f;
    for (int base = beg; base < end; base += 128) {
        int cl = min(128, end - base);
        __syncthreads();
        if (t < cl) {
            int s = perm[base + t];
            s_src[t] = s;
            s_alpha[t] = __expf(lrelu(a_s[s] + ad) - M) * inv;
        }
        __syncthreads();
        for (int j = 0; j < cl; j++)
            acc = fmaf(s_alpha[j], h[(size_t)s_src[j] * HID + t], acc);
    }
    float o = acc + bias[t];
    out[(size_t)n * HID + t] = elu_f(o);
}

// ---------------- segmented pooling (batch is sorted) ----------------
#define NPB 64
__global__ __launch_bounds__(128) void pool_seg_k(const float* __restrict__ out2,
                                                  const int* __restrict__ batch,
                                                  float* __restrict__ pooled,
                                                  float* __restrict__ cnt)
{
    int n0 = blockIdx.x * NPB;
    int n1 = min(n0 + NPB, NN);
    if (n0 >= n1) return;
    int t = threadIdx.x;
    int cur = batch[n0];
    float acc = 0.f;
    int count = 0;
    for (int n = n0; n < n1; n++) {
        int g = batch[n];
        if (g != cur) {
            atomicAdd(&pooled[cur * HID + t], acc);
            if (t == 0) atomicAdd(&cnt[cur], (float)count);
            acc = 0.f; count = 0; cur = g;
        }
        acc += out2[(size_t)n * HID + t];
        count++;
    }
    atomicAdd(&pooled[cur * HID + t], acc);
    if (t == 0) atomicAdd(&cnt[cur], (float)count);
}

__global__ void final_k(const float* __restrict__ pooled, const float* __restrict__ cnt,
                        const float* __restrict__ lw, const float* __restrict__ lb,
                        float* __restrict__ outp)
{
    int g = threadIdx.x;
    if (g < GG) {
        float acc = 0.f;
        for (int c = 0; c < HID; c++) acc += pooled[g * HID + c] * lw[c];
        float cc = fmaxf(cnt[g], 1.0f);
        outp[g] = acc / cc + lb[0];
    }
}

// ---------------- launch ----------------
extern "C" void kernel_launch(void* const* d_in, const int* in_sizes, int n_in,
                              void* d_out, int out_size, void* d_ws, size_t ws_size,
                              hipStream_t stream)
{
    const float* x    = (const float*)d_in[0];
    const int*   ei   = (const int*)d_in[1];
    const int*   batch= (const int*)d_in[2];
    const float* W1   = (const float*)d_in[3];
    const float* as1w = (const float*)d_in[4];
    const float* ad1w = (const float*)d_in[5];
    const float* b1   = (const float*)d_in[6];
    const float* W2   = (const float*)d_in[7];
    const float* as2w = (const float*)d_in[8];
    const float* ad2w = (const float*)d_in[9];
    const float* b2   = (const float*)d_in[10];
    const float* lw   = (const float*)d_in[11];
    const float* lb   = (const float*)d_in[12];
    float* outp = (float*)d_out;

    char* w = (char*)d_ws;
    size_t off = 0;
    auto alloc = [&](size_t bytes) -> char* {
        char* p = w + off;
        off += (bytes + 255) & ~(size_t)255;
        return p;
    };
    float* agg    = (float*)alloc((size_t)NN * F1 * 4);   // 61.4 MB; reused for hh2/out2
    float* out1   = (float*)alloc((size_t)NN * F1 * 4);   // 61.4 MB
    float* wt1    = (float*)alloc(1024 * 4);              // folded att vectors [2][4][128]
    float* a_s1   = (float*)alloc((size_t)NN * 4 * 4);
    float* a_d1   = (float*)alloc((size_t)NN * 4 * 4);
    float* a_s2   = (float*)alloc((size_t)NN * 4);
    float* a_d2   = (float*)alloc((size_t)NN * 4);
    int*   deg    = (int*)alloc((size_t)NN * 4);
    int*   rowptr = (int*)alloc((size_t)(NN + 1) * 4);
    int*   cursor = (int*)alloc((size_t)NN * 4);
    int*   perm   = (int*)alloc((size_t)ETOT * 4);
    float* pooled = (float*)alloc((size_t)GG * HID * 4);
    float* cnt    = (float*)alloc((size_t)GG * 4);
    float* hh2  = agg;                        // reuse: agg dead after head-GEMM
    float* out2 = agg + (size_t)NN * HID;     // disjoint from hh2 within agg region

    hipMemsetAsync(deg, 0, (size_t)NN * 4, stream);
    hipMemsetAsync(pooled, 0, (size_t)GG * HID * 4, stream);
    hipMemsetAsync(cnt, 0, (size_t)GG * 4, stream);

    // layer-1 scores via folded attention vectors (no h1 needed!)
    prep_att_k<<<8, 128, 0, stream>>>(W1, as1w, ad1w, wt1);
    score1_k<<<(NN + 15) / 16, 128, 0, stream>>>(x, wt1, a_s1, a_d1);

    // CSR by dst (shared across both layers)
    hist_k<<<(ETOT + 255) / 256, 256, 0, stream>>>(ei, deg);
    scan_k<<<1, 1024, 0, stream>>>(deg, rowptr);
    copy_int_k<<<(NN + 255) / 256, 256, 0, stream>>>(rowptr, cursor, NN);
    fill_k<<<(ETOT + 255) / 256, 256, 0, stream>>>(ei, cursor, perm);

    // aggregate x per (dst, head), then per-head GEMM with fused bias+ELU
    gat_agg1x<<<NN, 256, 0, stream>>>(x, a_s1, a_d1, rowptr, perm, agg);
    {
        dim3 g((NN + 63) / 64, 2, 4);  // M tiles x (N=128)/64 x heads
        gemm_generic<<<g, 256, 0, stream>>>(agg, F1, 128, W1, F1, 128,
                                            out1, F1, 128, b1, 128,
                                            NN, 128, IN_CH, 1);
    }

    // layer 2
    {
        dim3 g((NN + 63) / 64, 2, 1);
        gemm_generic<<<g, 256, 0, stream>>>(out1, F1, 0, W2, HID, 0,
                                            hh2, HID, 0, nullptr, 0,
                                            NN, HID, F1, 0);
    }
    att_scores_k<<<NN, 64, 0, stream>>>(hh2, as2w, ad2w, a_s2, a_d2);
    gat_agg2<<<NN, 128, 0, stream>>>(hh2, a_s2, a_d2, rowptr, perm, b2, out2);

    // pool + linear
    pool_seg_k<<<(NN + NPB - 1) / NPB, 128, 0, stream>>>(out2, batch, pooled, cnt);
    final_k<<<1, 64, 0, stream>>>(pooled, cnt, lw, lb, outp);
}